// Round 10
// baseline (227.390 us; speedup 1.0000x reference)
//
#include <hip/hip_runtime.h>

// int4-dequant GEMM: y[m,n] = sum_k x[m,k] * scale[n, k/128] * (q[n,k] - 8)
// x: (512,4096) f32 | weight_packed: (11008,2048) int32 (2 nibbles in low byte) |
// scales: (11008,32) f32 | out: (512,11008) f32
//
// R10: software-pipelined K-loop. R7/R8/R9 all plateaued at 457 TF (~101us)
// because the chain load->wait->dequant->barrier->MFMA is serialized per iter.
// Now: A double-buffered via global_load_lds, B register-pipelined (loads for
// kk+1 issued before MFMA(kk), so ~310 cyc of MFMA covers the load latency),
// LDS 48 KB + launch_bounds(256,3) -> 3 blocks/CU. Epilogue: R7's proven
// coalesced partials + reduce kernel.

typedef __attribute__((ext_vector_type(8)))  short short8;   // 16x16x32 A/B frag
typedef __attribute__((ext_vector_type(4)))  float f32x4;
typedef __attribute__((ext_vector_type(4)))  int   i32x4;
typedef __attribute__((ext_vector_type(2)))  int   i32x2;
typedef unsigned int   u32;
typedef unsigned short u16;

#define M_DIM 512
#define N_DIM 11008
#define K_DIM 4096
#define BM 128
#define BN 128
#define BK 64
#define KSPLIT 4
#define THREADS 256
#define NTILE_M 4
#define NTILE_N 86
#define NTILES  (NTILE_M * NTILE_N)  // 344
#define TILE_EL (BM * BN)            // 16384

#if defined(__has_builtin)
#  if __has_builtin(__builtin_amdgcn_cvt_pk_bf16_f32)
#    define HAVE_PK_BF16 1
#  endif
#  if __has_builtin(__builtin_amdgcn_global_load_lds)
#    define HAVE_GLLDS 1
#  endif
#endif
#ifndef HAVE_PK_BF16
#  define HAVE_PK_BF16 0
#endif
#ifndef HAVE_GLLDS
#  define HAVE_GLLDS 0
#endif

__device__ __forceinline__ unsigned int fbits(float f) {
    union { float f; unsigned int u; } c; c.f = f; return c.u;
}
__device__ __forceinline__ int pack2bf(float lo, float hi) {  // [hi|lo] bf16, RNE
#if HAVE_PK_BF16
    typedef __attribute__((ext_vector_type(2))) __bf16 bf16x2;
    bf16x2 p = __builtin_amdgcn_cvt_pk_bf16_f32(lo, hi);
    int r; __builtin_memcpy(&r, &p, 4);
    return r;
#else
    unsigned int ul = fbits(lo), uh = fbits(hi);
    unsigned int l = (ul + 0x7FFFu + ((ul >> 16) & 1u)) >> 16;
    unsigned int h = (uh + 0x7FFFu + ((uh >> 16) & 1u)) & 0xFFFF0000u;
    return (int)(h | l);
#endif
}

__device__ __forceinline__ void async16(const u16* g, u16* lds) {
#if HAVE_GLLDS
    __builtin_amdgcn_global_load_lds(
        (const __attribute__((address_space(1))) u32*)g,
        (__attribute__((address_space(3))) u32*)lds, 16, 0, 0);
#endif
}

// ---- x f32 -> bf16 ----
__global__ __launch_bounds__(THREADS)
void cvt_x(const float* __restrict__ x, u16* __restrict__ xw)
{
    int idx = (blockIdx.x * THREADS + threadIdx.x) * 4;
    f32x4 v = *(const f32x4*)(x + idx);
    i32x2 p;
    p[0] = pack2bf(v[0], v[1]);
    p[1] = pack2bf(v[2], v[3]);
    *(i32x2*)(xw + idx) = p;
}

// ---- pipelined fused GEMM (KS=4, needs xw + partials ws) ----
// LDS slot layout: slot(row,kc) = row*8 + (kc ^ (row&7)), 16B per slot.
__global__ __launch_bounds__(THREADS, 3)
void dq_gemm_pipe(const u16* __restrict__ xw, const int* __restrict__ wp,
                  const float* __restrict__ scales, float* __restrict__ partials)
{
    __shared__ __align__(16) u16 sA[2][BM * BK];  // 2 x 16 KB (A double buffer)
    __shared__ __align__(16) u16 sB[BN * BK];     // 16 KB

    const int t    = threadIdx.x;
    const int lane = t & 63;
    const int wave = t >> 6;
    const int bx   = blockIdx.x;

    // XCD swizzle: the 4 m-blocks of one (nb,ksp) share bx&7 (same XCD).
    int xs = bx & 7, s = bx >> 3;
    const int m_idx = s & 3;
    int q = (s >> 2) * 8 + xs;                    // [0,344)
    const int ksp = q & 3;
    const int nb  = q >> 2;
    const int m0 = m_idx * BM;
    const int n0 = nb * BN;
    const int k0 = ksp * (K_DIM / KSPLIT);
    const int KITERS = (K_DIM / KSPLIT) / BK;     // 16

    const int wm = (wave & 1) * 64;
    const int wn = (wave >> 1) * 64;
    const int lm   = lane & 15;
    const int quad = lane >> 4;

    // loop-invariant staging geometry (4 chunks/thread)
    int rowi[4], kcgi[4];
    #pragma unroll
    for (int i = 0; i < 4; ++i) {
        int ci = i * 256 + t;
        rowi[i] = ci >> 3;
        kcgi[i] = (ci & 7) ^ (rowi[i] & 7);
    }

    f32x4 acc[4][4] = {};
    i32x4 pv[4];
    float sc[4];

    auto load_b = [&](int kb) {
        #pragma unroll
        for (int i = 0; i < 4; ++i) {
            pv[i] = *(const i32x4*)(wp + (size_t)(n0 + rowi[i]) * (K_DIM / 2)
                                    + (kb >> 1) + kcgi[i] * 4);
            sc[i] = scales[(size_t)(n0 + rowi[i]) * 32 + (kb >> 7)];
        }
    };
    auto load_a_async = [&](int kb, int buf) {
#if HAVE_GLLDS
        #pragma unroll
        for (int i = 0; i < 4; ++i) {
            u16* lb = sA[buf] + (size_t)(i * 256 + wave * 64) * 8;  // wave-uniform
            async16(xw + (size_t)(m0 + rowi[i]) * K_DIM + kb + kcgi[i] * 8, lb);
        }
#else
        #pragma unroll
        for (int i = 0; i < 4; ++i) {
            int ci = i * 256 + t;
            *(i32x4*)(sA[buf] + (size_t)ci * 8) =
                *(const i32x4*)(xw + (size_t)(m0 + rowi[i]) * K_DIM + kb + kcgi[i] * 8);
        }
#endif
    };
    auto dequant_b = [&]() {
        #pragma unroll
        for (int i = 0; i < 4; ++i) {
            int ci = i * 256 + t;
            float sf = sc[i], ns8 = sf * -8.0f;
            i32x4 res;
            #pragma unroll
            for (int e = 0; e < 4; ++e) {
                int b = pv[i][e];
                res[e] = pack2bf((float)(b & 15) * sf + ns8,
                                 (float)((b >> 4) & 15) * sf + ns8);
            }
            *(i32x4*)(sB + (size_t)ci * 8) = res;
        }
    };

    // ---- prologue: tile 0 ----
    load_b(k0);
    load_a_async(k0, 0);
    dequant_b();          // waits pv (A-asyncs still in flight)
    __syncthreads();      // drains A-async(0); sA[0] + sB ready

    // ---- pipelined main loop ----
    for (int kk = 0; kk < KITERS; ++kk) {
        const bool has_next = (kk + 1 < KITERS);
        const int kb_next = k0 + (kk + 1) * BK;
        if (has_next) {
            load_b(kb_next);                 // in flight across MFMA below
            load_a_async(kb_next, (kk + 1) & 1);
        }

        const u16* sAc = sA[kk & 1];
        #pragma unroll
        for (int ks = 0; ks < BK; ks += 32) {
            const int kc = (ks >> 3) + quad;
            short8 a[4], b[4];
            #pragma unroll
            for (int i = 0; i < 4; ++i) {
                int row = wm + i * 16 + lm;
                a[i] = *(const short8*)&sAc[(row * 8 + (kc ^ (row & 7))) * 8];
            }
            #pragma unroll
            for (int j = 0; j < 4; ++j) {
                int row = wn + j * 16 + lm;
                b[j] = *(const short8*)&sB[(row * 8 + (kc ^ (row & 7))) * 8];
            }
            #pragma unroll
            for (int i = 0; i < 4; ++i)
                #pragma unroll
                for (int j = 0; j < 4; ++j)
                    acc[i][j] = __builtin_amdgcn_mfma_f32_16x16x32_bf16(
                        a[i], b[j], acc[i][j], 0, 0, 0);
        }

        __syncthreads();          // all sB reads done; drains next-tile loads
        if (has_next) {
            dequant_b();          // pv already resident (drained at barrier)
            __syncthreads();      // sB(kk+1) + sA[(kk+1)&1] ready
        }
    }

    // ---- epilogue: lane-coalesced partials (R7-proven) ----
    float* my = partials + ((size_t)(m_idx * NTILE_N + nb) * KSPLIT + ksp) * TILE_EL;
    #pragma unroll
    for (int i = 0; i < 4; ++i)
        #pragma unroll
        for (int j = 0; j < 4; ++j)
            *(f32x4*)(my + (i * 4 + j) * 1024 + t * 4) = acc[i][j];
}

// ---- basic fused GEMM (KS=1 fallback, unpipelined) ----
template<bool PRECVT>
__global__ __launch_bounds__(THREADS, 2)
void dq_gemm_basic(const u16* __restrict__ xw, const float* __restrict__ xf,
                   const int* __restrict__ wp, const float* __restrict__ scales,
                   float* __restrict__ out)
{
    __shared__ __align__(16) u16 sA[BM * BK];
    __shared__ __align__(16) u16 sB[BN * BK];

    const int t    = threadIdx.x;
    const int lane = t & 63;
    const int wave = t >> 6;
    const int m_idx = blockIdx.x & 3, nb = blockIdx.x >> 2;
    const int m0 = m_idx * BM, n0 = nb * BN;

    const int wm = (wave & 1) * 64, wn = (wave >> 1) * 64;
    const int lm = lane & 15, quad = lane >> 4;

    f32x4 acc[4][4] = {};

    for (int kb = 0; kb < K_DIM; kb += BK) {
        const int g = kb >> 7;
        i32x4 pv[4];
        float sc[4];
        #pragma unroll
        for (int i = 0; i < 4; ++i) {
            int ci = i * 256 + t, row = ci >> 3;
            int kcg = (ci & 7) ^ (row & 7);
            pv[i] = *(const i32x4*)(wp + (size_t)(n0 + row) * (K_DIM / 2) + (kb >> 1) + kcg * 4);
            sc[i] = scales[(size_t)(n0 + row) * 32 + g];
        }
        if constexpr (PRECVT) {
            #pragma unroll
            for (int i = 0; i < 4; ++i) {
                int ci = i * 256 + t, row = ci >> 3;
                int kcg = (ci & 7) ^ (row & 7);
                *(i32x4*)(sA + (size_t)ci * 8) =
                    *(const i32x4*)(xw + (size_t)(m0 + row) * K_DIM + kb + kcg * 8);
            }
        } else {
            #pragma unroll
            for (int i = 0; i < 8; ++i) {
                int c = i * 256 + t;
                int row = c >> 4, col4 = (c & 15) * 4;
                int kc = col4 >> 3, half = (col4 >> 2) & 1;
                f32x4 v = *(const f32x4*)(xf + (size_t)(m0 + row) * K_DIM + kb + col4);
                i32x2 p;
                p[0] = pack2bf(v[0], v[1]);
                p[1] = pack2bf(v[2], v[3]);
                *(i32x2*)(sA + (size_t)(row * 8 + (kc ^ (row & 7))) * 8 + half * 4) = p;
            }
        }
        #pragma unroll
        for (int i = 0; i < 4; ++i) {
            int ci = i * 256 + t;
            float sf = sc[i], ns8 = sf * -8.0f;
            i32x4 res;
            #pragma unroll
            for (int e = 0; e < 4; ++e) {
                int b = pv[i][e];
                res[e] = pack2bf((float)(b & 15) * sf + ns8,
                                 (float)((b >> 4) & 15) * sf + ns8);
            }
            *(i32x4*)(sB + (size_t)ci * 8) = res;
        }
        __syncthreads();
        #pragma unroll
        for (int ks = 0; ks < BK; ks += 32) {
            const int kc = (ks >> 3) + quad;
            short8 a[4], b[4];
            #pragma unroll
            for (int i = 0; i < 4; ++i) {
                int row = wm + i * 16 + lm;
                a[i] = *(const short8*)&sA[(row * 8 + (kc ^ (row & 7))) * 8];
            }
            #pragma unroll
            for (int j = 0; j < 4; ++j) {
                int row = wn + j * 16 + lm;
                b[j] = *(const short8*)&sB[(row * 8 + (kc ^ (row & 7))) * 8];
            }
            #pragma unroll
            for (int i = 0; i < 4; ++i)
                #pragma unroll
                for (int j = 0; j < 4; ++j)
                    acc[i][j] = __builtin_amdgcn_mfma_f32_16x16x32_bf16(
                        a[i], b[j], acc[i][j], 0, 0, 0);
        }
        __syncthreads();
    }

    #pragma unroll
    for (int i = 0; i < 4; ++i) {
        int mg = m0 + wm + i * 16 + quad * 4;
        #pragma unroll
        for (int j = 0; j < 4; ++j) {
            int ng = n0 + wn + j * 16 + lm;
            #pragma unroll
            for (int r = 0; r < 4; ++r)
                out[(size_t)(mg + r) * N_DIM + ng] = acc[i][j][r];
        }
    }
}

// ---- reduce: 688 blocks, block b = m-half h of tile b>>1 ----
__global__ __launch_bounds__(THREADS)
void reduce_k(const float* __restrict__ partials, float* __restrict__ out)
{
    __shared__ float sT[64][132];

    const int b    = blockIdx.x;
    const int tile = b >> 1;
    const int h    = b & 1;
    const int m_idx = tile / NTILE_N;
    const int nb    = tile % NTILE_N;
    const int m0 = m_idx * BM + h * 64;
    const int n0 = nb * BN;
    const int u  = threadIdx.x;

    const float* base = partials + (size_t)tile * KSPLIT * TILE_EL;

    #pragma unroll
    for (int it = 0; it < 8; ++it) {
        int idx = it * 256 + u;                    // [0,2048)
        int c   = idx >> 7;                        // [0,16)
        int tl  = idx & 127;
        int t   = (tl & 63) | (h << 6) | ((tl >> 6) << 7);
        int off = c * 1024 + t * 4;
        f32x4 s = *(const f32x4*)(base + off);
        s += *(const f32x4*)(base + TILE_EL + off);
        s += *(const f32x4*)(base + 2 * TILE_EL + off);
        s += *(const f32x4*)(base + 3 * TILE_EL + off);
        int i = c >> 2, j = c & 3;
        int lane = t & 63, wave = t >> 6;
        int mrow = i * 16 + (lane >> 4) * 4;
        int ncol = (wave >> 1) * 64 + j * 16 + (lane & 15);
        sT[mrow + 0][ncol] = s[0];
        sT[mrow + 1][ncol] = s[1];
        sT[mrow + 2][ncol] = s[2];
        sT[mrow + 3][ncol] = s[3];
    }
    __syncthreads();

    #pragma unroll
    for (int it = 0; it < 8; ++it) {
        int idx = it * 256 + u;
        int row = idx >> 5;
        int c4  = (idx & 31) * 4;
        f32x4 v = *(const f32x4*)&sT[row][c4];
        *(f32x4*)(out + (size_t)(m0 + row) * N_DIM + n0 + c4) = v;
    }
}

extern "C" void kernel_launch(void* const* d_in, const int* in_sizes, int n_in,
                              void* d_out, int out_size, void* d_ws, size_t ws_size,
                              hipStream_t stream) {
    (void)in_sizes; (void)n_in; (void)out_size;
    const float* x      = (const float*)d_in[0];
    const int*   wpck   = (const int*)d_in[1];
    const float* scales = (const float*)d_in[2];
    float*       out    = (float*)d_out;

    const size_t XW_BYTES   = (size_t)M_DIM * K_DIM * 2;                 //  4 MB
    const size_t PART_OFF   = XW_BYTES;
    const size_t PART_BYTES = (size_t)NTILES * KSPLIT * TILE_EL * 4;     // 90.2 MB

    if (ws_size >= PART_OFF + PART_BYTES) {
        u16*   xw   = (u16*)d_ws;
        float* part = (float*)((char*)d_ws + PART_OFF);
        cvt_x<<<(M_DIM * K_DIM) / (THREADS * 4), THREADS, 0, stream>>>(x, xw);
        dq_gemm_pipe<<<NTILES * KSPLIT, THREADS, 0, stream>>>(xw, wpck, scales, part);
        reduce_k<<<NTILES * 2, THREADS, 0, stream>>>(part, out);
    } else if (ws_size >= XW_BYTES) {
        u16* xw = (u16*)d_ws;
        cvt_x<<<(M_DIM * K_DIM) / (THREADS * 4), THREADS, 0, stream>>>(x, xw);
        dq_gemm_basic<true><<<NTILES, THREADS, 0, stream>>>(
            xw, x, wpck, scales, out);
    } else {
        dq_gemm_basic<false><<<NTILES, THREADS, 0, stream>>>(
            nullptr, x, wpck, scales, out);
    }
}

// Round 11
// 226.568 us; speedup vs baseline: 1.0036x; 1.0036x over previous
//
#include <hip/hip_runtime.h>

// int4-dequant GEMM: y[m,n] = sum_k x[m,k] * scale[n, k/128] * (q[n,k] - 8)
// x: (512,4096) f32 | weight_packed: (11008,2048) int32, value in [0,256) |
// scales: (11008,32) f32 | out: (512,11008) f32
//
// R11: single-barrier pipelined K-loop. R10's 2-barrier version didn't move
// (107us): next-tile loads drained at the first barrier (~300cyc cover) and
// dequant sat serial between barriers. Now: sA+sB both double-buffered, B
// global loads 2 tiles ahead (ping-pong regs), dequant(kk+1) + MFMA(kk)
// between barriers covers the one drain point (~600cyc). Dequant pack cut
// ~2x via +0x8000 round + v_perm_b32 (one inst packs both bf16 halves).

typedef __attribute__((ext_vector_type(8)))  short short8;   // 16x16x32 A/B frag
typedef __attribute__((ext_vector_type(4)))  float f32x4;
typedef __attribute__((ext_vector_type(4)))  int   i32x4;
typedef __attribute__((ext_vector_type(2)))  int   i32x2;
typedef unsigned int   u32;
typedef unsigned short u16;

#define M_DIM 512
#define N_DIM 11008
#define K_DIM 4096
#define BM 128
#define BN 128
#define BK 64
#define KSPLIT 4
#define THREADS 256
#define NTILE_M 4
#define NTILE_N 86
#define NTILES  (NTILE_M * NTILE_N)  // 344
#define TILE_EL (BM * BN)            // 16384

#if defined(__has_builtin)
#  if __has_builtin(__builtin_amdgcn_global_load_lds)
#    define HAVE_GLLDS 1
#  endif
#endif
#ifndef HAVE_GLLDS
#  define HAVE_GLLDS 0
#endif

__device__ __forceinline__ unsigned int fbits(float f) {
    union { float f; unsigned int u; } c; c.f = f; return c.u;
}
// RNE pack (epilogue/cvt use; exact)
__device__ __forceinline__ int pack2bf(float lo, float hi) {
    unsigned int ul = fbits(lo), uh = fbits(hi);
    unsigned int l = (ul + 0x7FFFu + ((ul >> 16) & 1u)) >> 16;
    unsigned int h = (uh + 0x7FFFu + ((uh >> 16) & 1u)) & 0xFFFF0000u;
    return (int)(h | l);
}
// fast pack: round-half-away (+0x8000) then byte-perm both high halves.
// diff vs RNE only on exact ties (1 ulp bf16) — inputs are finite.
__device__ __forceinline__ int pack2bf_fast(float lo, float hi) {
    unsigned int u0 = fbits(lo) + 0x8000u;
    unsigned int u1 = fbits(hi) + 0x8000u;
    return (int)__builtin_amdgcn_perm(u1, u0, 0x07060302u);
}

__device__ __forceinline__ void async16(const u16* g, u16* lds) {
#if HAVE_GLLDS
    __builtin_amdgcn_global_load_lds(
        (const __attribute__((address_space(1))) u32*)g,
        (__attribute__((address_space(3))) u32*)lds, 16, 0, 0);
#endif
}

// ---- x f32 -> bf16 ----
__global__ __launch_bounds__(THREADS)
void cvt_x(const float* __restrict__ x, u16* __restrict__ xw)
{
    int idx = (blockIdx.x * THREADS + threadIdx.x) * 4;
    f32x4 v = *(const f32x4*)(x + idx);
    i32x2 p;
    p[0] = pack2bf(v[0], v[1]);
    p[1] = pack2bf(v[2], v[3]);
    *(i32x2*)(xw + idx) = p;
}

// ---- single-barrier pipelined fused GEMM (KS=4) ----
// LDS slot layout per buffer: slot(row,kc) = row*8 + (kc ^ (row&7)), 16B/slot.
__global__ __launch_bounds__(THREADS, 2)
void dq_gemm_pipe(const u16* __restrict__ xw, const int* __restrict__ wp,
                  const float* __restrict__ scales, float* __restrict__ partials)
{
    __shared__ __align__(16) u16 sA[2][BM * BK];  // 2 x 16 KB
    __shared__ __align__(16) u16 sB[2][BN * BK];  // 2 x 16 KB  (total 64 KB)

    const int t    = threadIdx.x;
    const int lane = t & 63;
    const int wave = t >> 6;
    const int bx   = blockIdx.x;

    // XCD swizzle: the 4 m-blocks of one (nb,ksp) share bx&7 (same XCD).
    int xs = bx & 7, s = bx >> 3;
    const int m_idx = s & 3;
    int q = (s >> 2) * 8 + xs;                    // [0,344)
    const int ksp = q & 3;
    const int nb  = q >> 2;
    const int m0 = m_idx * BM;
    const int n0 = nb * BN;
    const int k0 = ksp * (K_DIM / KSPLIT);
    const int g0 = k0 >> 7;
    const int KITERS = (K_DIM / KSPLIT) / BK;     // 16

    const int wm = (wave & 1) * 64;
    const int wn = (wave >> 1) * 64;
    const int lm   = lane & 15;
    const int quad = lane >> 4;

    // loop-invariant staging geometry (4 chunks/thread)
    int rowi[4], kcgi[4];
    const int*   pb[4];   // B packed base per chunk (at k0)
    const float* ps[4];   // scale row base
    const u16*   pa[4];   // A base per chunk (at k0)
    #pragma unroll
    for (int i = 0; i < 4; ++i) {
        int ci = i * 256 + t;
        rowi[i] = ci >> 3;
        kcgi[i] = (ci & 7) ^ (rowi[i] & 7);
        pb[i] = wp + (size_t)(n0 + rowi[i]) * (K_DIM / 2) + (k0 >> 1) + kcgi[i] * 4;
        ps[i] = scales + (size_t)(n0 + rowi[i]) * 32;
        pa[i] = xw + (size_t)(m0 + rowi[i]) * K_DIM + k0 + kcgi[i] * 8;
    }

    f32x4 acc[4][4] = {};
    i32x4 pv[2][4];
    float sc[2][4];

    // issue B global loads for tile kk into reg slot
    auto issue_b = [&](int slot, int kk) {
        #pragma unroll
        for (int i = 0; i < 4; ++i) {
            pv[slot][i] = *(const i32x4*)(pb[i] + kk * (BK / 2));
            sc[slot][i] = ps[i][g0 + (kk >> 1)];
        }
    };
    // A -> LDS async for tile kk into buffer buf
    auto issue_a = [&](int kk, int buf) {
#if HAVE_GLLDS
        #pragma unroll
        for (int i = 0; i < 4; ++i) {
            u16* lb = sA[buf] + (size_t)(i * 256 + wave * 64) * 8;  // wave-uniform
            async16(pa[i] + kk * BK, lb);
        }
#else
        #pragma unroll
        for (int i = 0; i < 4; ++i) {
            int ci = i * 256 + t;
            *(i32x4*)(sA[buf] + (size_t)ci * 8) = *(const i32x4*)(pa[i] + kk * BK);
        }
#endif
    };
    // dequant reg slot -> sB buffer. b in [0,256): hi nibble = b>>4 (no mask).
    auto dequant_to = [&](int slot, int buf) {
        #pragma unroll
        for (int i = 0; i < 4; ++i) {
            int ci = i * 256 + t;
            float sf = sc[slot][i], ns8 = sf * -8.0f;
            i32x4 res;
            #pragma unroll
            for (int e = 0; e < 4; ++e) {
                int b = pv[slot][i][e];
                res[e] = pack2bf_fast((float)(b & 15) * sf + ns8,
                                      (float)(b >> 4) * sf + ns8);
            }
            *(i32x4*)(sB[buf] + (size_t)ci * 8) = res;
        }
    };
    auto mfma_tile = [&](int buf) {
        const u16* sAc = sA[buf];
        const u16* sBc = sB[buf];
        #pragma unroll
        for (int ks = 0; ks < BK; ks += 32) {
            const int kc = (ks >> 3) + quad;
            short8 a[4], b[4];
            #pragma unroll
            for (int i = 0; i < 4; ++i) {
                int row = wm + i * 16 + lm;
                a[i] = *(const short8*)&sAc[(row * 8 + (kc ^ (row & 7))) * 8];
            }
            #pragma unroll
            for (int j = 0; j < 4; ++j) {
                int row = wn + j * 16 + lm;
                b[j] = *(const short8*)&sBc[(row * 8 + (kc ^ (row & 7))) * 8];
            }
            #pragma unroll
            for (int i = 0; i < 4; ++i)
                #pragma unroll
                for (int j = 0; j < 4; ++j)
                    acc[i][j] = __builtin_amdgcn_mfma_f32_16x16x32_bf16(
                        a[i], b[j], acc[i][j], 0, 0, 0);
        }
    };

    // ---- prologue: tile 0 staged, tile 1 B-loads in flight ----
    issue_b(0, 0);
    issue_a(0, 0);
    dequant_to(0, 0);      // waits pv[0]
    issue_b(1, 1);         // tile 1 -> slot 1
    __syncthreads();       // drains A-async(0) (and pv[1] — prologue only)

    // ---- main loop: one barrier per iter ----
    // invariant at top of iter kk (p=kk&1): tile kk in sA[p]/sB[p]; tile kk+1's
    // B-regs in slot p^1 (issued a full iter ago); slot p free.
    auto step = [&](int kk, int p) {
        if (kk + 1 < KITERS) issue_a(kk + 1, p ^ 1);
        if (kk + 2 < KITERS) issue_b(p, kk + 2);
        if (kk + 1 < KITERS) dequant_to(p ^ 1, p ^ 1);  // latency long covered
        mfma_tile(p);
        __syncthreads();   // drains async-A(kk+1) + pv(kk+2); cover = dequant+MFMA
    };
    for (int kk = 0; kk < KITERS; kk += 2) {
        step(kk, 0);
        step(kk + 1, 1);
    }

    // ---- epilogue: lane-coalesced partials (R7-proven) ----
    float* my = partials + ((size_t)(m_idx * NTILE_N + nb) * KSPLIT + ksp) * TILE_EL;
    #pragma unroll
    for (int i = 0; i < 4; ++i)
        #pragma unroll
        for (int j = 0; j < 4; ++j)
            *(f32x4*)(my + (i * 4 + j) * 1024 + t * 4) = acc[i][j];
}

// ---- basic fused GEMM (fallback, KS=1) ----
template<bool PRECVT>
__global__ __launch_bounds__(THREADS, 2)
void dq_gemm_basic(const u16* __restrict__ xw, const float* __restrict__ xf,
                   const int* __restrict__ wp, const float* __restrict__ scales,
                   float* __restrict__ out)
{
    __shared__ __align__(16) u16 sA[BM * BK];
    __shared__ __align__(16) u16 sB[BN * BK];

    const int t    = threadIdx.x;
    const int lane = t & 63;
    const int wave = t >> 6;
    const int m_idx = blockIdx.x & 3, nb = blockIdx.x >> 2;
    const int m0 = m_idx * BM, n0 = nb * BN;

    const int wm = (wave & 1) * 64, wn = (wave >> 1) * 64;
    const int lm = lane & 15, quad = lane >> 4;

    f32x4 acc[4][4] = {};

    for (int kb = 0; kb < K_DIM; kb += BK) {
        const int g = kb >> 7;
        i32x4 pv[4];
        float sc[4];
        #pragma unroll
        for (int i = 0; i < 4; ++i) {
            int ci = i * 256 + t, row = ci >> 3;
            int kcg = (ci & 7) ^ (row & 7);
            pv[i] = *(const i32x4*)(wp + (size_t)(n0 + row) * (K_DIM / 2) + (kb >> 1) + kcg * 4);
            sc[i] = scales[(size_t)(n0 + row) * 32 + g];
        }
        if constexpr (PRECVT) {
            #pragma unroll
            for (int i = 0; i < 4; ++i) {
                int ci = i * 256 + t, row = ci >> 3;
                int kcg = (ci & 7) ^ (row & 7);
                *(i32x4*)(sA + (size_t)ci * 8) =
                    *(const i32x4*)(xw + (size_t)(m0 + row) * K_DIM + kb + kcg * 8);
            }
        } else {
            #pragma unroll
            for (int i = 0; i < 8; ++i) {
                int c = i * 256 + t;
                int row = c >> 4, col4 = (c & 15) * 4;
                int kc = col4 >> 3, half = (col4 >> 2) & 1;
                f32x4 v = *(const f32x4*)(xf + (size_t)(m0 + row) * K_DIM + kb + col4);
                i32x2 p;
                p[0] = pack2bf(v[0], v[1]);
                p[1] = pack2bf(v[2], v[3]);
                *(i32x2*)(sA + (size_t)(row * 8 + (kc ^ (row & 7))) * 8 + half * 4) = p;
            }
        }
        #pragma unroll
        for (int i = 0; i < 4; ++i) {
            int ci = i * 256 + t;
            float sf = sc[i], ns8 = sf * -8.0f;
            i32x4 res;
            #pragma unroll
            for (int e = 0; e < 4; ++e) {
                int b = pv[i][e];
                res[e] = pack2bf_fast((float)(b & 15) * sf + ns8,
                                      (float)(b >> 4) * sf + ns8);
            }
            *(i32x4*)(sB + (size_t)ci * 8) = res;
        }
        __syncthreads();
        #pragma unroll
        for (int ks = 0; ks < BK; ks += 32) {
            const int kc = (ks >> 3) + quad;
            short8 a[4], b[4];
            #pragma unroll
            for (int i = 0; i < 4; ++i) {
                int row = wm + i * 16 + lm;
                a[i] = *(const short8*)&sA[(row * 8 + (kc ^ (row & 7))) * 8];
            }
            #pragma unroll
            for (int j = 0; j < 4; ++j) {
                int row = wn + j * 16 + lm;
                b[j] = *(const short8*)&sB[(row * 8 + (kc ^ (row & 7))) * 8];
            }
            #pragma unroll
            for (int i = 0; i < 4; ++i)
                #pragma unroll
                for (int j = 0; j < 4; ++j)
                    acc[i][j] = __builtin_amdgcn_mfma_f32_16x16x32_bf16(
                        a[i], b[j], acc[i][j], 0, 0, 0);
        }
        __syncthreads();
    }

    #pragma unroll
    for (int i = 0; i < 4; ++i) {
        int mg = m0 + wm + i * 16 + quad * 4;
        #pragma unroll
        for (int j = 0; j < 4; ++j) {
            int ng = n0 + wn + j * 16 + lm;
            #pragma unroll
            for (int r = 0; r < 4; ++r)
                out[(size_t)(mg + r) * N_DIM + ng] = acc[i][j][r];
        }
    }
}

// ---- reduce: 688 blocks, block b = m-half h of tile b>>1 ----
__global__ __launch_bounds__(THREADS)
void reduce_k(const float* __restrict__ partials, float* __restrict__ out)
{
    __shared__ float sT[64][132];

    const int b    = blockIdx.x;
    const int tile = b >> 1;
    const int h    = b & 1;
    const int m_idx = tile / NTILE_N;
    const int nb    = tile % NTILE_N;
    const int m0 = m_idx * BM + h * 64;
    const int n0 = nb * BN;
    const int u  = threadIdx.x;

    const float* base = partials + (size_t)tile * KSPLIT * TILE_EL;

    #pragma unroll
    for (int it = 0; it < 8; ++it) {
        int idx = it * 256 + u;                    // [0,2048)
        int c   = idx >> 7;                        // [0,16)
        int tl  = idx & 127;
        int t   = (tl & 63) | (h << 6) | ((tl >> 6) << 7);
        int off = c * 1024 + t * 4;
        f32x4 s = *(const f32x4*)(base + off);
        s += *(const f32x4*)(base + TILE_EL + off);
        s += *(const f32x4*)(base + 2 * TILE_EL + off);
        s += *(const f32x4*)(base + 3 * TILE_EL + off);
        int i = c >> 2, j = c & 3;
        int lane = t & 63, wave = t >> 6;
        int mrow = i * 16 + (lane >> 4) * 4;
        int ncol = (wave >> 1) * 64 + j * 16 + (lane & 15);
        sT[mrow + 0][ncol] = s[0];
        sT[mrow + 1][ncol] = s[1];
        sT[mrow + 2][ncol] = s[2];
        sT[mrow + 3][ncol] = s[3];
    }
    __syncthreads();

    #pragma unroll
    for (int it = 0; it < 8; ++it) {
        int idx = it * 256 + u;
        int row = idx >> 5;
        int c4  = (idx & 31) * 4;
        f32x4 v = *(const f32x4*)&sT[row][c4];
        *(f32x4*)(out + (size_t)(m0 + row) * N_DIM + n0 + c4) = v;
    }
}

extern "C" void kernel_launch(void* const* d_in, const int* in_sizes, int n_in,
                              void* d_out, int out_size, void* d_ws, size_t ws_size,
                              hipStream_t stream) {
    (void)in_sizes; (void)n_in; (void)out_size;
    const float* x      = (const float*)d_in[0];
    const int*   wpck   = (const int*)d_in[1];
    const float* scales = (const float*)d_in[2];
    float*       out    = (float*)d_out;

    const size_t XW_BYTES   = (size_t)M_DIM * K_DIM * 2;                 //  4 MB
    const size_t PART_OFF   = XW_BYTES;
    const size_t PART_BYTES = (size_t)NTILES * KSPLIT * TILE_EL * 4;     // 90.2 MB

    if (ws_size >= PART_OFF + PART_BYTES) {
        u16*   xw   = (u16*)d_ws;
        float* part = (float*)((char*)d_ws + PART_OFF);
        cvt_x<<<(M_DIM * K_DIM) / (THREADS * 4), THREADS, 0, stream>>>(x, xw);
        dq_gemm_pipe<<<NTILES * KSPLIT, THREADS, 0, stream>>>(xw, wpck, scales, part);
        reduce_k<<<NTILES * 2, THREADS, 0, stream>>>(part, out);
    } else if (ws_size >= XW_BYTES) {
        u16* xw = (u16*)d_ws;
        cvt_x<<<(M_DIM * K_DIM) / (THREADS * 4), THREADS, 0, stream>>>(x, xw);
        dq_gemm_basic<true><<<NTILES, THREADS, 0, stream>>>(
            xw, x, wpck, scales, out);
    } else {
        dq_gemm_basic<false><<<NTILES, THREADS, 0, stream>>>(
            nullptr, x, wpck, scales, out);
    }
}